// Round 12
// baseline (63.959 us; speedup 1.0000x reference)
//
#include <hip/hip_runtime.h>

#define BB 1024
#define NN 128
#define VV 200
#define HH 400

__device__ inline float wave_sum(float v){
  for (int o=32;o>0;o>>=1) v += __shfl_down(v,o);
  return v;
}
__device__ inline float xsum(float v){
  for (int o=1;o<64;o<<=1) v += __shfl_xor(v,o);
  return v;
}
__device__ inline float xmax(float v){
  for (int o=1;o<64;o<<=1) v = fmaxf(v,__shfl_xor(v,o));
  return v;
}

struct FrontP {
  const float *merged, *x, *a;
  const float *Wq_aug,*bq_aug,*Wk_aug,*bk_aug,*Wv_aug,*bv_aug;
  const float *Wq_o,*bq_o,*Wk_o,*bk_o,*Wv_o,*bv_o;
  const float *W0,*b0,*W1,*b1,*W2,*b2;
  float *t_buf;
  float *out;
};

// ================= K1: self-contained attn superblocks + mlp units ==========
// blocks 0..255: attention (4 batches, one per wave, no LDS, no syncthreads)
// blocks 256..1151: mlp units (8 batches x 64-wide j-tile); Q1 partials are
// atomicAdd'ed straight into out[b], out[2BB+b], out[3BB+b] (out pre-zeroed).
__global__ __launch_bounds__(256) void k_front(FrontP p)
{
  const int tid = threadIdx.x;
  const int wv = tid>>6, lane = tid&63;

  if (blockIdx.x < 256){
    // ---------------- attention: one wave per batch, fully in-register ------
    const int b = blockIdx.x*4 + wv;
    const float* base = p.merged + (size_t)b*NN*15;

    // issue the cold-HBM row loads FIRST; q/fold compute hides their latency
    float m0[15], m1[15];
    const float* r0 = base + (size_t)lane*15;
    const float* r1 = base + (size_t)(lane+64)*15;
    #pragma unroll
    for (int i=0;i<15;i++){ m0[i]=r0[i]; m1[i]=r1[i]; }

    float sub_bus = base[0], sub_loc = base[2];
    float eg[7];
    eg[0]=0.0f;
    #pragma unroll
    for (int i=1;i<7;i++) eg[i]=base[i];

    // q channels owned by this lane: c, c+64, c+128, c+192(lane<8 only)
    const int c0=lane, c1=lane+64, c2=lane+128;
    const bool v3 = (lane<8);
    const int c3 = v3 ? lane+192 : 199;

    float qa[4], qo[4];
    #pragma unroll
    for (int r=0;r<4;r++){
      int c = (r==0)?c0:(r==1)?c1:(r==2)?c2:c3;
      float sa_ = p.bq_aug[c], so_ = p.bq_o[c];
      #pragma unroll
      for (int i=1;i<7;i++){
        sa_ += eg[i]*p.Wq_aug[i*VV+c];
        so_ += eg[i]*p.Wq_o[i*VV+c];
      }
      qa[r]=sa_; qo[r]=so_;
    }
    if (!v3){ qa[3]=0.0f; qo[3]=0.0f; }

    // fold Wk into q: 23 single-round reductions
    float wkqa[14], wkqo[7];
    #pragma unroll
    for (int f=0;f<14;f++){
      const float* wk = p.Wk_aug + f*VV;
      float pp = qa[0]*wk[c0] + qa[1]*wk[c1] + qa[2]*wk[c2] + qa[3]*wk[c3];
      wkqa[f]=xsum(pp);
    }
    float qbka = xsum(qa[0]*p.bk_aug[c0] + qa[1]*p.bk_aug[c1]
                    + qa[2]*p.bk_aug[c2] + qa[3]*p.bk_aug[c3]);
    #pragma unroll
    for (int f=0;f<7;f++){
      const float* wk = p.Wk_o + f*VV;
      float pp = qo[0]*wk[c0] + qo[1]*wk[c1] + qo[2]*wk[c2] + qo[3]*wk[c3];
      wkqo[f]=xsum(pp);
    }
    float qbko = xsum(qo[0]*p.bk_o[c0] + qo[1]*p.bk_o[c1]
                    + qo[2]*p.bk_o[c2] + qo[3]*p.bk_o[c3]);

    m0[0]-=sub_bus; m0[7]-=sub_bus;
    m1[0]-=sub_bus; m1[7]-=sub_bus;

    const float scale = 0.07071067811865475f; // 1/sqrt(200)
    float sa0=qbka, sa1=qbka, so0=qbko, so1=qbko;
    #pragma unroll
    for (int f=0;f<14;f++){ sa0+=m0[f]*wkqa[f]; sa1+=m1[f]*wkqa[f]; }
    #pragma unroll
    for (int f=0;f<7;f++){ so0+=m0[f]*wkqo[f]; so1+=m1[f]*wkqo[f]; }
    sa0*=scale; sa1*=scale; so0*=scale; so1*=scale;

    float fl0=m0[14], fl1=m1[14], lo0=m0[2], lo1=m1[2];
    bool um0=(lo0<sub_loc)&&(fl0==1.0f), um1=(lo1<sub_loc)&&(fl1==1.0f);
    bool dm0=(lo0>sub_loc)&&(fl0==1.0f), dm1=(lo1>sub_loc)&&(fl1==1.0f);
    bool f00=(fl0==0.0f), f01=(fl1==0.0f);
    unsigned long long bal0=__ballot(f00), bal1=__ballot(f01);
    unsigned long long below=(1ull<<lane)-1ull;
    int prior0=__popcll(bal0&below);
    int prior1=__popcll(bal0)+__popcll(bal1&below);
    bool om0=f00&&(prior0>0), om1=f01&&(prior1>0);

    const float NINF=-3.0e38f;
    float mu_ = xmax(fmaxf(um0?sa0:NINF, um1?sa1:NINF));
    bool anyu = mu_>-1e38f;
    float eu0 = um0?expf(sa0-mu_):0.0f, eu1 = um1?expf(sa1-mu_):0.0f;
    float su = xsum(eu0+eu1);
    float ivu = anyu?1.0f/su:0.0f;
    float wu0=eu0*ivu, wu1=eu1*ivu;

    float md_ = xmax(fmaxf(dm0?sa0:NINF, dm1?sa1:NINF));
    bool anyd = md_>-1e38f;
    float ed0 = dm0?expf(sa0-md_):0.0f, ed1 = dm1?expf(sa1-md_):0.0f;
    float sd = xsum(ed0+ed1);
    float ivd = anyd?1.0f/sd:0.0f;
    float wd0=ed0*ivd, wd1=ed1*ivd;

    float mo_ = xmax(fmaxf(om0?so0:NINF, om1?so1:NINF));
    bool anyo = mo_>-1e38f;
    float eo0 = om0?expf(so0-mo_):0.0f, eo1 = om1?expf(so1-mo_):0.0f;
    float so = xsum(eo0+eo1);
    float ivo = anyo?1.0f/so:0.0f;
    float wo0=eo0*ivo, wo1=eo1*ivo;

    float wfu[14], wfd[14], wfo[7];
    #pragma unroll
    for (int f=0;f<14;f++){
      wfu[f]=xsum(wu0*m0[f]+wu1*m1[f]);
      wfd[f]=xsum(wd0*m0[f]+wd1*m1[f]);
    }
    #pragma unroll
    for (int f=0;f<7;f++) wfo[f]=xsum(wo0*m0[f]+wo1*m1[f]);

    float* tb = p.t_buf + (size_t)b*600;
    #pragma unroll
    for (int rep=0;rep<4;rep++){
      int c = lane + rep*64;
      if (c < VV){
        float uv=p.bv_aug[c], dv=p.bv_aug[c], ov=p.bv_o[c];
        #pragma unroll
        for (int f=0;f<14;f++){
          float w=p.Wv_aug[f*VV+c];
          uv+=wfu[f]*w; dv+=wfd[f]*w;
        }
        #pragma unroll
        for (int f=0;f<7;f++) ov+=wfo[f]*p.Wv_o[f*VV+c];
        if(!anyu) uv=0.0f;
        if(!anyd) dv=0.0f;
        if(!anyo) ov=0.0f;
        tb[c]=uv; tb[200+c]=dv; tb[400+c]=ov;
      }
    }
  } else {
    // ---------------- mlp unit: 8 batches x 64-wide j-tile ----------------
    __shared__ float smem[8*HH + 4*64*9 + 32];
    unsigned mu = blockIdx.x - 256;
    int js = mu >> 7;          // 0..6
    int xg = mu & 127;
    int bb = xg*8;
    float* h1s  = smem;                 // [8][HH]
    float* part = smem + 8*HH;          // [4][64][9]
    float* ego  = smem + 8*HH + 4*64*9; // [8][4]
    if (tid<32){
      int bl=tid>>2, j=tid&3;
      int b=bb+bl;
      ego[bl*4+j] = (j<3) ? p.x[(size_t)b*NN*8 + 4 + j] : p.a[b];
    }
    __syncthreads();
    for (int idx=tid; idx<8*HH; idx+=256){
      int bl = idx/HH, i = idx - bl*HH;
      float v = p.b0[i] + ego[bl*4+0]*p.W0[i]      + ego[bl*4+1]*p.W0[HH+i]
                        + ego[bl*4+2]*p.W0[2*HH+i] + ego[bl*4+3]*p.W0[3*HH+i];
      h1s[bl*HH+i] = fmaxf(v,0.0f);
    }
    __syncthreads();
    int jl = tid & 63;
    int ic = tid >> 6;
    int j  = js*64 + jl;
    bool jok = (j < HH);
    int jc = jok ? j : (HH-1);
    float acc[8]={0,0,0,0,0,0,0,0};
    {
      const float* w1p = p.W1 + jc;
      int i0 = ic*100;
      #pragma unroll 4
      for (int i=i0;i<i0+100;i++){
        float w = w1p[(size_t)i*HH];
        acc[0]+=h1s[0*HH+i]*w; acc[1]+=h1s[1*HH+i]*w;
        acc[2]+=h1s[2*HH+i]*w; acc[3]+=h1s[3*HH+i]*w;
        acc[4]+=h1s[4*HH+i]*w; acc[5]+=h1s[5*HH+i]*w;
        acc[6]+=h1s[6*HH+i]*w; acc[7]+=h1s[7*HH+i]*w;
      }
    }
    for (int bl=0;bl<8;bl++) part[(ic*64+jl)*9+bl]=acc[bl];
    __syncthreads();
    if (tid < 64){
      float bj = p.b1[jc], w2 = p.W2[jc];
      float badd = (js==0) ? p.b2[0] : 0.0f;   // add b2 exactly once per b
      for (int bl=0;bl<8;bl++){
        float s = part[(0*64+jl)*9+bl]+part[(1*64+jl)*9+bl]
                + part[(2*64+jl)*9+bl]+part[(3*64+jl)*9+bl];
        s += bj;
        float contrib = jok ? fmaxf(s,0.0f)*w2 : 0.0f;
        float tot = wave_sum(contrib);
        if (jl==0){
          int b = bb+bl;
          float q = tot + badd;
          atomicAdd(p.out + b,        q);   // Q1
          atomicAdd(p.out + 2*BB + b, q);   // G1 partial
          atomicAdd(p.out + 3*BB + b, q);   // G2 partial
        }
      }
    }
  }
}

// ================= K2: BN stats over batch (float4, each elem once) =========
__global__ __launch_bounds__(256) void k_bnstats(const float* __restrict__ t_buf,
    float* __restrict__ mean_out, float* __restrict__ rstd_out)
{
  int c0 = blockIdx.x*4;          // 150 blocks x 4 channels
  int tid=threadIdx.x; int wv=tid>>6, lane=tid&63;
  float s[4]={0,0,0,0}, s2[4]={0,0,0,0};
  #pragma unroll 2
  for (int b=tid;b<BB;b+=256){
    float4 v = *reinterpret_cast<const float4*>(t_buf + (size_t)b*600 + c0);
    s[0]+=v.x; s[1]+=v.y; s[2]+=v.z; s[3]+=v.w;
    s2[0]+=v.x*v.x; s2[1]+=v.y*v.y; s2[2]+=v.z*v.z; s2[3]+=v.w*v.w;
  }
  __shared__ float ls[4][4], ls2[4][4];
  for (int c=0;c<4;c++){ s[c]=wave_sum(s[c]); s2[c]=wave_sum(s2[c]); }
  if (lane==0){
    for (int c=0;c<4;c++){ ls[wv][c]=s[c]; ls2[wv][c]=s2[c]; }
  }
  __syncthreads();
  if (tid<4){
    float S =ls[0][tid]+ls[1][tid]+ls[2][tid]+ls[3][tid];
    float S2=ls2[0][tid]+ls2[1][tid]+ls2[2][tid]+ls2[3][tid];
    float mean = S*(1.0f/BB);
    float var  = S2*(1.0f/BB) - mean*mean;
    mean_out[c0+tid]=mean;
    rstd_out[c0+tid]=rsqrtf(var+1e-5f);
  }
}

// ================= K3: BN apply + heads (768 blocks), atomic finalize =======
// Head k contributes (s + b4[k]) to: out[BB+b],out[3BB+b] (odd k -> A2/G2)
// or out[2BB+b] (even k -> G1). Q1 parts already added by k_front.
__global__ __launch_bounds__(256,4) void k_heads(
    const float* __restrict__ t_buf, const float* __restrict__ mean_in,
    const float* __restrict__ rstd_in,
    const float* __restrict__ bn_g, const float* __restrict__ bn_b,
    const float* __restrict__ W3, const float* __restrict__ b3,
    const float* __restrict__ W4, const float* __restrict__ b4,
    float* __restrict__ out)
{
  int bb = blockIdx.x*8;          // 128 groups of 8 b
  int k  = blockIdx.y;            // 0..5
  int tid=threadIdx.x, wv=tid>>6, lane=tid&63;
  int t3 = k>>1;
  __shared__ float tn[8][200];
  __shared__ float red[4][8];

  for (int idx=tid; idx<1600; idx+=256){
    int bl=idx/200, v=idx-bl*200;
    int c = t3*200+v;
    tn[bl][v] = bn_g[v]*(t_buf[(size_t)(bb+bl)*600+c]-mean_in[c])*rstd_in[c]+bn_b[v];
  }
  __syncthreads();

  int g = tid;
  int gc = (g<200)? g : 199;
  bool act = (g<200);
  float acc[8];
  {
    float bias = b3[k*200+gc];
    for (int bl=0;bl<8;bl++) acc[bl]=bias;
  }
  const float* w3p = W3 + (size_t)k*40000 + gc;
  const float4* tn4 = reinterpret_cast<const float4*>(&tn[0][0]); // [8][50]
  #pragma unroll 2
  for (int v4=0; v4<50; v4++){
    int v = v4*4;
    float w0 = w3p[(size_t)v*200];
    float w1 = w3p[(size_t)(v+1)*200];
    float w2 = w3p[(size_t)(v+2)*200];
    float w3v= w3p[(size_t)(v+3)*200];
    #pragma unroll
    for (int bl=0;bl<8;bl++){
      float4 t = tn4[bl*50+v4];
      acc[bl] += t.x*w0 + t.y*w1 + t.z*w2 + t.w*w3v;
    }
  }
  float w4 = W4[k*200+gc];
  float contrib[8];
  #pragma unroll
  for (int bl=0;bl<8;bl++){
    float h = acc[bl]>0.f ? acc[bl] : (expf(acc[bl])-1.0f);
    contrib[bl] = act ? h*w4 : 0.0f;
  }
  #pragma unroll
  for (int bl=0;bl<8;bl++) contrib[bl]=wave_sum(contrib[bl]);
  if (lane==0) for (int bl=0;bl<8;bl++) red[wv][bl]=contrib[bl];
  __syncthreads();
  if (tid<8){
    float s = red[0][tid]+red[1][tid]+red[2][tid]+red[3][tid] + b4[k];
    int b = bb+tid;
    if (k & 1){                       // odd head -> A2 -> out row 1 and G2
      atomicAdd(out + BB + b,   s);
      atomicAdd(out + 3*BB + b, s);
    } else {                          // even head -> A1 -> G1 only
      atomicAdd(out + 2*BB + b, s);
    }
  }
}

extern "C" void kernel_launch(void* const* d_in, const int* in_sizes, int n_in,
                              void* d_out, int out_size, void* d_ws, size_t ws_size,
                              hipStream_t stream)
{
  (void)in_sizes; (void)n_in; (void)out_size; (void)ws_size;
  float* ws  = (float*)d_ws;
  float* out = (float*)d_out;

  FrontP P;
  P.merged=(const float*)d_in[0];
  P.x     =(const float*)d_in[1];
  P.a     =(const float*)d_in[2];
  P.Wq_aug=(const float*)d_in[3];  P.bq_aug=(const float*)d_in[4];
  P.Wk_aug=(const float*)d_in[5];  P.bk_aug=(const float*)d_in[6];
  P.Wv_aug=(const float*)d_in[7];  P.bv_aug=(const float*)d_in[8];
  P.Wq_o  =(const float*)d_in[9];  P.bq_o  =(const float*)d_in[10];
  P.Wk_o  =(const float*)d_in[11]; P.bk_o  =(const float*)d_in[12];
  P.Wv_o  =(const float*)d_in[13]; P.bv_o  =(const float*)d_in[14];
  P.W0    =(const float*)d_in[21]; P.b0    =(const float*)d_in[22];
  P.W1    =(const float*)d_in[23]; P.b1    =(const float*)d_in[24];
  P.W2    =(const float*)d_in[25]; P.b2    =(const float*)d_in[26];
  const float* bn_g =(const float*)d_in[15];
  const float* bn_b =(const float*)d_in[16];
  const float* W3   =(const float*)d_in[17];
  const float* b3   =(const float*)d_in[18];
  const float* W4   =(const float*)d_in[19];
  const float* b4   =(const float*)d_in[20];

  P.t_buf = ws;                     // 1024*600
  P.out   = out;
  float* mean_b = ws + 614400;      // 600
  float* rstd_b = ws + 615000;      // 600

  hipMemsetAsync((void*)out, 0, (size_t)(4*BB+1)*sizeof(float), stream);
  hipLaunchKernelGGL(k_front, dim3(256+896), dim3(256), 0, stream, P);
  hipLaunchKernelGGL(k_bnstats, dim3(150), dim3(256), 0, stream,
      P.t_buf, mean_b, rstd_b);
  hipLaunchKernelGGL(k_heads, dim3(128,6), dim3(256), 0, stream,
      P.t_buf, mean_b, rstd_b, bn_g, bn_b, W3, b3, W4, b4, out);
}

// Round 13
// 53.146 us; speedup vs baseline: 1.2035x; 1.2035x over previous
//
#include <hip/hip_runtime.h>

#define BB 1024
#define NN 128
#define VV 200
#define HH 400

__device__ inline float wave_sum(float v){
  for (int o=32;o>0;o>>=1) v += __shfl_down(v,o);
  return v;
}
__device__ inline float xsum(float v){
  for (int o=1;o<64;o<<=1) v += __shfl_xor(v,o);
  return v;
}
__device__ inline float xmax(float v){
  for (int o=1;o<64;o<<=1) v = fmaxf(v,__shfl_xor(v,o));
  return v;
}

struct FrontP {
  const float *merged, *x, *a;
  const float *Wq_aug,*bq_aug,*Wk_aug,*bk_aug,*Wv_aug,*bv_aug;
  const float *Wq_o,*bq_o,*Wk_o,*bk_o,*Wv_o,*bv_o;
  const float *W0,*b0,*W1,*b1,*W2;
  float *t_buf, *mlp_part;
};

// ================= K1: self-contained attn superblocks + mlp units ==========
// blocks 0..255: attention (4 batches, one per wave, no LDS, no syncthreads)
// blocks 256..1151: mlp units (8 batches x 64-wide j-tile) -> mlp_part
__global__ __launch_bounds__(256) void k_front(FrontP p)
{
  const int tid = threadIdx.x;
  const int wv = tid>>6, lane = tid&63;

  if (blockIdx.x < 256){
    // ---------------- attention: one wave per batch, fully in-register ------
    const int b = blockIdx.x*4 + wv;
    const float* base = p.merged + (size_t)b*NN*15;

    // issue the cold-HBM row loads FIRST; q/fold compute hides their latency
    float m0[15], m1[15];
    const float* r0 = base + (size_t)lane*15;
    const float* r1 = base + (size_t)(lane+64)*15;
    #pragma unroll
    for (int i=0;i<15;i++){ m0[i]=r0[i]; m1[i]=r1[i]; }

    float sub_bus = base[0], sub_loc = base[2];
    float eg[7];
    eg[0]=0.0f;
    #pragma unroll
    for (int i=1;i<7;i++) eg[i]=base[i];

    // q channels owned by this lane: c, c+64, c+128, c+192(lane<8 only)
    const int c0=lane, c1=lane+64, c2=lane+128;
    const bool v3 = (lane<8);
    const int c3 = v3 ? lane+192 : 199;

    float qa[4], qo[4];
    #pragma unroll
    for (int r=0;r<4;r++){
      int c = (r==0)?c0:(r==1)?c1:(r==2)?c2:c3;
      float sa_ = p.bq_aug[c], so_ = p.bq_o[c];
      #pragma unroll
      for (int i=1;i<7;i++){
        sa_ += eg[i]*p.Wq_aug[i*VV+c];
        so_ += eg[i]*p.Wq_o[i*VV+c];
      }
      qa[r]=sa_; qo[r]=so_;
    }
    if (!v3){ qa[3]=0.0f; qo[3]=0.0f; }

    // fold Wk into q: 23 single-round reductions
    float wkqa[14], wkqo[7];
    #pragma unroll
    for (int f=0;f<14;f++){
      const float* wk = p.Wk_aug + f*VV;
      float pp = qa[0]*wk[c0] + qa[1]*wk[c1] + qa[2]*wk[c2] + qa[3]*wk[c3];
      wkqa[f]=xsum(pp);
    }
    float qbka = xsum(qa[0]*p.bk_aug[c0] + qa[1]*p.bk_aug[c1]
                    + qa[2]*p.bk_aug[c2] + qa[3]*p.bk_aug[c3]);
    #pragma unroll
    for (int f=0;f<7;f++){
      const float* wk = p.Wk_o + f*VV;
      float pp = qo[0]*wk[c0] + qo[1]*wk[c1] + qo[2]*wk[c2] + qo[3]*wk[c3];
      wkqo[f]=xsum(pp);
    }
    float qbko = xsum(qo[0]*p.bk_o[c0] + qo[1]*p.bk_o[c1]
                    + qo[2]*p.bk_o[c2] + qo[3]*p.bk_o[c3]);

    m0[0]-=sub_bus; m0[7]-=sub_bus;
    m1[0]-=sub_bus; m1[7]-=sub_bus;

    const float scale = 0.07071067811865475f; // 1/sqrt(200)
    float sa0=qbka, sa1=qbka, so0=qbko, so1=qbko;
    #pragma unroll
    for (int f=0;f<14;f++){ sa0+=m0[f]*wkqa[f]; sa1+=m1[f]*wkqa[f]; }
    #pragma unroll
    for (int f=0;f<7;f++){ so0+=m0[f]*wkqo[f]; so1+=m1[f]*wkqo[f]; }
    sa0*=scale; sa1*=scale; so0*=scale; so1*=scale;

    float fl0=m0[14], fl1=m1[14], lo0=m0[2], lo1=m1[2];
    bool um0=(lo0<sub_loc)&&(fl0==1.0f), um1=(lo1<sub_loc)&&(fl1==1.0f);
    bool dm0=(lo0>sub_loc)&&(fl0==1.0f), dm1=(lo1>sub_loc)&&(fl1==1.0f);
    bool f00=(fl0==0.0f), f01=(fl1==0.0f);
    unsigned long long bal0=__ballot(f00), bal1=__ballot(f01);
    unsigned long long below=(1ull<<lane)-1ull;
    int prior0=__popcll(bal0&below);
    int prior1=__popcll(bal0)+__popcll(bal1&below);
    bool om0=f00&&(prior0>0), om1=f01&&(prior1>0);

    const float NINF=-3.0e38f;
    float mu_ = xmax(fmaxf(um0?sa0:NINF, um1?sa1:NINF));
    bool anyu = mu_>-1e38f;
    float eu0 = um0?expf(sa0-mu_):0.0f, eu1 = um1?expf(sa1-mu_):0.0f;
    float su = xsum(eu0+eu1);
    float ivu = anyu?1.0f/su:0.0f;
    float wu0=eu0*ivu, wu1=eu1*ivu;

    float md_ = xmax(fmaxf(dm0?sa0:NINF, dm1?sa1:NINF));
    bool anyd = md_>-1e38f;
    float ed0 = dm0?expf(sa0-md_):0.0f, ed1 = dm1?expf(sa1-md_):0.0f;
    float sd = xsum(ed0+ed1);
    float ivd = anyd?1.0f/sd:0.0f;
    float wd0=ed0*ivd, wd1=ed1*ivd;

    float mo_ = xmax(fmaxf(om0?so0:NINF, om1?so1:NINF));
    bool anyo = mo_>-1e38f;
    float eo0 = om0?expf(so0-mo_):0.0f, eo1 = om1?expf(so1-mo_):0.0f;
    float so = xsum(eo0+eo1);
    float ivo = anyo?1.0f/so:0.0f;
    float wo0=eo0*ivo, wo1=eo1*ivo;

    float wfu[14], wfd[14], wfo[7];
    #pragma unroll
    for (int f=0;f<14;f++){
      wfu[f]=xsum(wu0*m0[f]+wu1*m1[f]);
      wfd[f]=xsum(wd0*m0[f]+wd1*m1[f]);
    }
    #pragma unroll
    for (int f=0;f<7;f++) wfo[f]=xsum(wo0*m0[f]+wo1*m1[f]);

    float* tb = p.t_buf + (size_t)b*600;
    #pragma unroll
    for (int rep=0;rep<4;rep++){
      int c = lane + rep*64;
      if (c < VV){
        float uv=p.bv_aug[c], dv=p.bv_aug[c], ov=p.bv_o[c];
        #pragma unroll
        for (int f=0;f<14;f++){
          float w=p.Wv_aug[f*VV+c];
          uv+=wfu[f]*w; dv+=wfd[f]*w;
        }
        #pragma unroll
        for (int f=0;f<7;f++) ov+=wfo[f]*p.Wv_o[f*VV+c];
        if(!anyu) uv=0.0f;
        if(!anyd) dv=0.0f;
        if(!anyo) ov=0.0f;
        tb[c]=uv; tb[200+c]=dv; tb[400+c]=ov;
      }
    }
  } else {
    // ---------------- mlp unit: 8 batches x 64-wide j-tile ----------------
    __shared__ float smem[8*HH + 4*64*9 + 32];
    unsigned mu = blockIdx.x - 256;
    int js = mu >> 7;          // 0..6
    int xg = mu & 127;
    int bb = xg*8;
    float* h1s  = smem;                 // [8][HH]
    float* part = smem + 8*HH;          // [4][64][9]
    float* ego  = smem + 8*HH + 4*64*9; // [8][4]
    if (tid<32){
      int bl=tid>>2, j=tid&3;
      int b=bb+bl;
      ego[bl*4+j] = (j<3) ? p.x[(size_t)b*NN*8 + 4 + j] : p.a[b];
    }
    __syncthreads();
    for (int idx=tid; idx<8*HH; idx+=256){
      int bl = idx/HH, i = idx - bl*HH;
      float v = p.b0[i] + ego[bl*4+0]*p.W0[i]      + ego[bl*4+1]*p.W0[HH+i]
                        + ego[bl*4+2]*p.W0[2*HH+i] + ego[bl*4+3]*p.W0[3*HH+i];
      h1s[bl*HH+i] = fmaxf(v,0.0f);
    }
    __syncthreads();
    int jl = tid & 63;
    int ic = tid >> 6;
    int j  = js*64 + jl;
    bool jok = (j < HH);
    int jc = jok ? j : (HH-1);
    float acc[8]={0,0,0,0,0,0,0,0};
    {
      const float* w1p = p.W1 + jc;
      int i0 = ic*100;
      #pragma unroll 4
      for (int i=i0;i<i0+100;i++){
        float w = w1p[(size_t)i*HH];
        acc[0]+=h1s[0*HH+i]*w; acc[1]+=h1s[1*HH+i]*w;
        acc[2]+=h1s[2*HH+i]*w; acc[3]+=h1s[3*HH+i]*w;
        acc[4]+=h1s[4*HH+i]*w; acc[5]+=h1s[5*HH+i]*w;
        acc[6]+=h1s[6*HH+i]*w; acc[7]+=h1s[7*HH+i]*w;
      }
    }
    for (int bl=0;bl<8;bl++) part[(ic*64+jl)*9+bl]=acc[bl];
    __syncthreads();
    if (tid < 64){
      float bj = p.b1[jc], w2 = p.W2[jc];
      for (int bl=0;bl<8;bl++){
        float s = part[(0*64+jl)*9+bl]+part[(1*64+jl)*9+bl]
                + part[(2*64+jl)*9+bl]+part[(3*64+jl)*9+bl];
        s += bj;
        float contrib = jok ? fmaxf(s,0.0f)*w2 : 0.0f;
        float tot = wave_sum(contrib);
        if (jl==0) p.mlp_part[(size_t)(bb+bl)*8 + js] = tot;
      }
    }
  }
}

// ====== K2: BN stats (blocks 0..149) + Q1-combine & out-init (150..153) =====
// blocks 150..153: b = (bid-150)*256+tid; q = sum(mlp_part[b])+b2;
//   out[b]=q, out[BB+b]=0, out[2BB+b]=q, out[3BB+b]=q  (G-rows seeded with Q1
//   so k_heads only needs to add head contributions). out[4BB]=0.
__global__ __launch_bounds__(256) void k_bnstats(const float* __restrict__ t_buf,
    float* __restrict__ mean_out, float* __restrict__ rstd_out,
    const float* __restrict__ mlp_part, const float* __restrict__ b2,
    float* __restrict__ out)
{
  int tid=threadIdx.x; int wv=tid>>6, lane=tid&63;
  if (blockIdx.x < 150){
    int c0 = blockIdx.x*4;          // 150 blocks x 4 channels
    float s[4]={0,0,0,0}, s2[4]={0,0,0,0};
    #pragma unroll 2
    for (int b=tid;b<BB;b+=256){
      float4 v = *reinterpret_cast<const float4*>(t_buf + (size_t)b*600 + c0);
      s[0]+=v.x; s[1]+=v.y; s[2]+=v.z; s[3]+=v.w;
      s2[0]+=v.x*v.x; s2[1]+=v.y*v.y; s2[2]+=v.z*v.z; s2[3]+=v.w*v.w;
    }
    __shared__ float ls[4][4], ls2[4][4];
    for (int c=0;c<4;c++){ s[c]=wave_sum(s[c]); s2[c]=wave_sum(s2[c]); }
    if (lane==0){
      for (int c=0;c<4;c++){ ls[wv][c]=s[c]; ls2[wv][c]=s2[c]; }
    }
    __syncthreads();
    if (tid<4){
      float S =ls[0][tid]+ls[1][tid]+ls[2][tid]+ls[3][tid];
      float S2=ls2[0][tid]+ls2[1][tid]+ls2[2][tid]+ls2[3][tid];
      float mean = S*(1.0f/BB);
      float var  = S2*(1.0f/BB) - mean*mean;
      mean_out[c0+tid]=mean;
      rstd_out[c0+tid]=rsqrtf(var+1e-5f);
    }
  } else {
    int b = (blockIdx.x-150)*256 + tid;   // 4 blocks -> 1024 b
    const float* mp = mlp_part + (size_t)b*8;
    float q = mp[0]+mp[1]+mp[2]+mp[3]+mp[4]+mp[5]+mp[6] + b2[0];
    out[b]      = q;     // Q1 (final)
    out[BB+b]   = 0.0f;  // A2 base
    out[2*BB+b] = q;     // G1 base (Q1 seeded)
    out[3*BB+b] = q;     // G2 base (Q1 seeded)
    if (blockIdx.x==150 && tid==0) out[4*BB]=0.0f;  // reg
  }
}

// ================= K3: BN apply + heads (768 blocks), atomic finish =========
// Head k adds (s+b4[k]) to: odd k -> out[BB+b] (A2) and out[3BB+b] (G2);
// even k -> out[2BB+b] (G1). Bases were seeded by k_bnstats.
__global__ __launch_bounds__(256,4) void k_heads(
    const float* __restrict__ t_buf, const float* __restrict__ mean_in,
    const float* __restrict__ rstd_in,
    const float* __restrict__ bn_g, const float* __restrict__ bn_b,
    const float* __restrict__ W3, const float* __restrict__ b3,
    const float* __restrict__ W4, const float* __restrict__ b4,
    float* __restrict__ out)
{
  int bb = blockIdx.x*8;          // 128 groups of 8 b
  int k  = blockIdx.y;            // 0..5
  int tid=threadIdx.x, wv=tid>>6, lane=tid&63;
  int t3 = k>>1;
  __shared__ float tn[8][200];
  __shared__ float red[4][8];

  for (int idx=tid; idx<1600; idx+=256){
    int bl=idx/200, v=idx-bl*200;
    int c = t3*200+v;
    tn[bl][v] = bn_g[v]*(t_buf[(size_t)(bb+bl)*600+c]-mean_in[c])*rstd_in[c]+bn_b[v];
  }
  __syncthreads();

  int g = tid;
  int gc = (g<200)? g : 199;
  bool act = (g<200);
  float acc[8];
  {
    float bias = b3[k*200+gc];
    for (int bl=0;bl<8;bl++) acc[bl]=bias;
  }
  const float* w3p = W3 + (size_t)k*40000 + gc;
  const float4* tn4 = reinterpret_cast<const float4*>(&tn[0][0]); // [8][50]
  #pragma unroll 2
  for (int v4=0; v4<50; v4++){
    int v = v4*4;
    float w0 = w3p[(size_t)v*200];
    float w1 = w3p[(size_t)(v+1)*200];
    float w2 = w3p[(size_t)(v+2)*200];
    float w3v= w3p[(size_t)(v+3)*200];
    #pragma unroll
    for (int bl=0;bl<8;bl++){
      float4 t = tn4[bl*50+v4];
      acc[bl] += t.x*w0 + t.y*w1 + t.z*w2 + t.w*w3v;
    }
  }
  float w4 = W4[k*200+gc];
  float contrib[8];
  #pragma unroll
  for (int bl=0;bl<8;bl++){
    float h = acc[bl]>0.f ? acc[bl] : (expf(acc[bl])-1.0f);
    contrib[bl] = act ? h*w4 : 0.0f;
  }
  #pragma unroll
  for (int bl=0;bl<8;bl++) contrib[bl]=wave_sum(contrib[bl]);
  if (lane==0) for (int bl=0;bl<8;bl++) red[wv][bl]=contrib[bl];
  __syncthreads();
  if (tid<8){
    float s = red[0][tid]+red[1][tid]+red[2][tid]+red[3][tid] + b4[k];
    int b = bb+tid;
    if (k & 1){                       // odd head -> A2 and G2
      atomicAdd(out + BB + b,   s);
      atomicAdd(out + 3*BB + b, s);
    } else {                          // even head -> G1
      atomicAdd(out + 2*BB + b, s);
    }
  }
}

extern "C" void kernel_launch(void* const* d_in, const int* in_sizes, int n_in,
                              void* d_out, int out_size, void* d_ws, size_t ws_size,
                              hipStream_t stream)
{
  (void)in_sizes; (void)n_in; (void)out_size; (void)ws_size;
  float* ws  = (float*)d_ws;
  float* out = (float*)d_out;

  FrontP P;
  P.merged=(const float*)d_in[0];
  P.x     =(const float*)d_in[1];
  P.a     =(const float*)d_in[2];
  P.Wq_aug=(const float*)d_in[3];  P.bq_aug=(const float*)d_in[4];
  P.Wk_aug=(const float*)d_in[5];  P.bk_aug=(const float*)d_in[6];
  P.Wv_aug=(const float*)d_in[7];  P.bv_aug=(const float*)d_in[8];
  P.Wq_o  =(const float*)d_in[9];  P.bq_o  =(const float*)d_in[10];
  P.Wk_o  =(const float*)d_in[11]; P.bk_o  =(const float*)d_in[12];
  P.Wv_o  =(const float*)d_in[13]; P.bv_o  =(const float*)d_in[14];
  P.W0    =(const float*)d_in[21]; P.b0    =(const float*)d_in[22];
  P.W1    =(const float*)d_in[23]; P.b1    =(const float*)d_in[24];
  P.W2    =(const float*)d_in[25];
  const float* bn_g =(const float*)d_in[15];
  const float* bn_b =(const float*)d_in[16];
  const float* W3   =(const float*)d_in[17];
  const float* b3   =(const float*)d_in[18];
  const float* W4   =(const float*)d_in[19];
  const float* b4   =(const float*)d_in[20];
  const float* b2   =(const float*)d_in[26];

  P.t_buf    = ws;                  // 1024*600
  float* mean_b = ws + 614400;      // 600
  float* rstd_b = ws + 615000;      // 600
  P.mlp_part = ws + 615600;         // 1024*8

  hipLaunchKernelGGL(k_front, dim3(256+896), dim3(256), 0, stream, P);
  hipLaunchKernelGGL(k_bnstats, dim3(154), dim3(256), 0, stream,
      P.t_buf, mean_b, rstd_b, P.mlp_part, b2, out);
  hipLaunchKernelGGL(k_heads, dim3(128,6), dim3(256), 0, stream,
      P.t_buf, mean_b, rstd_b, bn_g, bn_b, W3, b3, W4, b4, out);
}